// Round 3
// baseline (1918.323 us; speedup 1.0000x reference)
//
#include <hip/hip_runtime.h>
#include <hip/hip_bf16.h>
#include <math.h>

#define B_ 4
#define L_ 5
#define C_ 64
#define H_ 100
#define W_ 352
#define HW_ (H_ * W_)

typedef __hip_bfloat16 bf16;

__device__ __forceinline__ float b2f(bf16 v) { return __bfloat162float(v); }
__device__ __forceinline__ bf16 f2b(float v) { return __float2bfloat16(v); }

template <typename T> __device__ __forceinline__ T from_f(float v);
template <> __device__ __forceinline__ float from_f<float>(float v) { return v; }
template <> __device__ __forceinline__ bf16 from_f<bf16>(float v) { return f2b(v); }

// ---------------------------------------------------------------------------
// Kernel 1: theta precompute. theta[b][l] from pairwise_t_matrix[b,0,l]  (fp32)
// ---------------------------------------------------------------------------
__global__ void theta_kernel(const float* __restrict__ t, float* __restrict__ th) {
    int tid = threadIdx.x;
    if (tid >= B_ * L_) return;
    int b = tid / L_, l = tid % L_;
    const float* p = t + b * (L_ * L_ * 16) + l * 16;  // [b][0][l][4][4]
    float* o = th + tid * 6;
    o[0] = p[0];
    o[1] = p[1] * (100.0f / 352.0f);           // * H/W
    o[2] = p[3] * (2.0f / 281.6f);             // / (2*0.4*W) * 2
    o[3] = p[4] * (352.0f / 100.0f);           // * W/H
    o[4] = p[5];
    o[5] = p[7] * (2.0f / 80.0f);              // / (2*0.4*H) * 2
}

// ---------------------------------------------------------------------------
// Kernel 2: warp (bilinear, zero-pad, align-corners) + max over L, x & vox.
// fp32 inputs -> bf16 aggregates.
// ---------------------------------------------------------------------------
__global__ __launch_bounds__(256) void warp_max_kernel(
    const float* __restrict__ x, const float* __restrict__ vox,
    const float* __restrict__ th,
    bf16* __restrict__ feat_agg, bf16* __restrict__ vox_agg) {
    int p = blockIdx.x * 256 + threadIdx.x;
    if (p >= HW_) return;
    int c = blockIdx.y;
    int b = blockIdx.z;
    int w = p % W_;
    int h = p / W_;
    float gx = fmaf((float)w, 2.0f / 351.0f, -1.0f);
    float gy = fmaf((float)h, 2.0f / 99.0f, -1.0f);
    float fmx = -INFINITY, vmx = -INFINITY;
#pragma unroll
    for (int l = 0; l < L_; l++) {
        const float* t = th + (b * L_ + l) * 6;
        float sx = t[0] * gx + t[1] * gy + t[2];
        float sy = t[3] * gx + t[4] * gy + t[5];
        float px = (sx + 1.0f) * 0.5f * 351.0f;
        float py = (sy + 1.0f) * 0.5f * 99.0f;
        float x0f = floorf(px), y0f = floorf(py);
        float fx = px - x0f, fy = py - y0f;
        int x0 = (int)x0f, y0 = (int)y0f;
        int x1 = x0 + 1, y1 = y0 + 1;
        bool vx0 = (x0 >= 0) && (x0 <= W_ - 1);
        bool vx1 = (x1 >= 0) && (x1 <= W_ - 1);
        bool vy0 = (y0 >= 0) && (y0 <= H_ - 1);
        bool vy1 = (y1 >= 0) && (y1 <= H_ - 1);
        int x0c = min(max(x0, 0), W_ - 1), x1c = min(max(x1, 0), W_ - 1);
        int y0c = min(max(y0, 0), H_ - 1), y1c = min(max(y1, 0), H_ - 1);
        float w00 = (1.0f - fx) * (1.0f - fy) * ((vx0 && vy0) ? 1.0f : 0.0f);
        float w10 = fx * (1.0f - fy) * ((vx1 && vy0) ? 1.0f : 0.0f);
        float w01 = (1.0f - fx) * fy * ((vx0 && vy1) ? 1.0f : 0.0f);
        float w11 = fx * fy * ((vx1 && vy1) ? 1.0f : 0.0f);
        int base = ((b * L_ + l) * C_ + c) * HW_;
        int i00 = y0c * W_ + x0c, i10 = y0c * W_ + x1c;
        int i01 = y1c * W_ + x0c, i11 = y1c * W_ + x1c;
        float s = x[base + i00] * w00 + x[base + i10] * w10 +
                  x[base + i01] * w01 + x[base + i11] * w11;
        float v = vox[base + i00] * w00 + vox[base + i10] * w10 +
                  vox[base + i01] * w01 + vox[base + i11] * w11;
        fmx = fmaxf(fmx, s);
        vmx = fmaxf(vmx, v);
    }
    int o = (b * C_ + c) * HW_ + p;
    feat_agg[o] = f2b(fmx);
    vox_agg[o] = f2b(vmx);
}

// ---------------------------------------------------------------------------
// Kernel 3: direct 3x3 conv 64->64 + scale/bias + ReLU.
// bf16 input, fp32 weights; templated output (fp32 for ve->d_out, bf16 for fe)
// ---------------------------------------------------------------------------
template <typename OT>
__global__ __launch_bounds__(256) void conv3x3_kernel(
    const bf16* __restrict__ in, const float* __restrict__ wgt,
    const float* __restrict__ cb, const float* __restrict__ g,
    const float* __restrict__ bt, OT* __restrict__ out) {
    int p = blockIdx.x * 256 + threadIdx.x;
    if (p >= HW_) return;
    int co0 = blockIdx.y * 4;
    int b = blockIdx.z;
    int w = p % W_, h = p / W_;
    float acc[4] = {0.0f, 0.0f, 0.0f, 0.0f};
    for (int ci = 0; ci < C_; ci++) {
        const bf16* ip = in + (b * C_ + ci) * HW_;
        const float* wp = wgt + (co0 * C_ + ci) * 9;  // co stride = 576
        float wv[4][9];
#pragma unroll
        for (int j = 0; j < 4; j++)
#pragma unroll
            for (int t = 0; t < 9; t++) wv[j][t] = wp[j * 576 + t];
#pragma unroll
        for (int kh = 0; kh < 3; kh++) {
            int hy = h + kh - 1;
            bool vh = (hy >= 0) && (hy < H_);
            int rb = hy * W_;
#pragma unroll
            for (int kw = 0; kw < 3; kw++) {
                int wx = w + kw - 1;
                bool v = vh && (wx >= 0) && (wx < W_);
                float val = v ? b2f(ip[rb + wx]) : 0.0f;
                int t = kh * 3 + kw;
                acc[0] = fmaf(val, wv[0][t], acc[0]);
                acc[1] = fmaf(val, wv[1][t], acc[1]);
                acc[2] = fmaf(val, wv[2][t], acc[2]);
                acc[3] = fmaf(val, wv[3][t], acc[3]);
            }
        }
    }
#pragma unroll
    for (int j = 0; j < 4; j++) {
        int co = co0 + j;
        float sc = g[co];
        float bi = cb[co] * sc + bt[co];
        float r = fmaxf(fmaf(acc[j], sc, bi), 0.0f);
        out[(b * C_ + co) * HW_ + p] = from_f<OT>(r);
    }
}

// ---------------------------------------------------------------------------
// Kernel 4: attention gate. block = 32 k-lanes x 8 pixels.
// ve is fp32 (d_out), fe is bf16 (ws).
// ---------------------------------------------------------------------------
__global__ __launch_bounds__(256) void attn_kernel(
    const float* __restrict__ ve, const bf16* __restrict__ fe,
    const float* __restrict__ aw1, const float* __restrict__ ab1,
    const float* __restrict__ aw2, const float* __restrict__ ab2,
    float* __restrict__ a0map) {
    __shared__ float wlds[32 * 129];  // pad 128 -> 129 to break bank conflicts
    int tid = threadIdx.x;
    for (int i = tid; i < 32 * 128; i += 256) {
        int k = i >> 7, c = i & 127;
        wlds[k * 129 + c] = aw1[i];
    }
    __syncthreads();
    int k = tid & 31;
    int pp = tid >> 5;
    int pixel = blockIdx.x * 8 + pp;
    bool valid = pixel < B_ * HW_;
    if (!valid) pixel = 0;
    int b = pixel / HW_, p = pixel % HW_;
    float acc = ab1[k];
    const float* wrow = wlds + k * 129;
    for (int c = 0; c < C_; c++) {
        float vec = ve[(b * C_ + c) * HW_ + p];
        float fec = b2f(fe[(b * C_ + c) * HW_ + p]);
        acc = fmaf(wrow[c], vec, acc);
        acc = fmaf(wrow[64 + c], fec, acc);
    }
    float a1 = fmaxf(acc, 0.0f);
    float z0 = aw2[k] * a1;
    float z1 = aw2[32 + k] * a1;
#pragma unroll
    for (int m = 16; m >= 1; m >>= 1) {  // stays within each 32-lane k-group
        z0 += __shfl_xor(z0, m, 64);
        z1 += __shfl_xor(z1, m, 64);
    }
    if (k == 0 && valid) {
        z0 += ab2[0];
        z1 += ab2[1];
        a0map[pixel] = 1.0f / (1.0f + __expf(z1 - z0));
    }
}

// ---------------------------------------------------------------------------
// Kernel 5: out = ego + a0*ve + (1-a0)*fe   (ve lives in d_out; in-place)
// ---------------------------------------------------------------------------
__global__ __launch_bounds__(256) void fuse_kernel(
    const float* __restrict__ x, const bf16* __restrict__ fe,
    const float* __restrict__ a0map, float* __restrict__ out_ve) {
    int p = blockIdx.x * 256 + threadIdx.x;
    if (p >= HW_) return;
    int c = blockIdx.y, b = blockIdx.z;
    float a0 = a0map[b * HW_ + p];
    int o = (b * C_ + c) * HW_ + p;
    float ego = x[((b * L_) * C_ + c) * HW_ + p];  // xb[b,0,c]
    float vv = out_ve[o];                          // ve (in d_out)
    float ff = b2f(fe[o]);
    out_ve[o] = ego + a0 * vv + (1.0f - a0) * ff;
}

// ---------------------------------------------------------------------------
// Workspace layout (~36 MiB):
//   th     @ ws + 0            (480 B)
//   slotA  @ ws + 4096         (18,022,400 B bf16)  vox_agg -> fe
//   slotB  @ ws + 4096 + szA   (18,022,400 B bf16)  feat_agg -> a0map(fp32)
//   ve lives in d_out (fp32, 36 MB); fuse is in-place on d_out.
// ---------------------------------------------------------------------------
extern "C" void kernel_launch(void* const* d_in, const int* in_sizes, int n_in,
                              void* d_out, int out_size, void* d_ws, size_t ws_size,
                              hipStream_t stream) {
    const float* x   = (const float*)d_in[0];
    const float* vox = (const float*)d_in[1];
    // d_in[2] det_bev: dead (multiplied by 0.0 in reference)
    const float* pt  = (const float*)d_in[3];
    // d_in[4] record_len: unused
    const float* vw  = (const float*)d_in[5];
    const float* vb  = (const float*)d_in[6];
    const float* vg  = (const float*)d_in[7];
    const float* vbt = (const float*)d_in[8];
    const float* fw  = (const float*)d_in[9];
    const float* fb  = (const float*)d_in[10];
    const float* fg  = (const float*)d_in[11];
    const float* fbt = (const float*)d_in[12];
    const float* aw1 = (const float*)d_in[13];
    const float* ab1 = (const float*)d_in[14];
    const float* aw2 = (const float*)d_in[15];
    const float* ab2 = (const float*)d_in[16];
    float* out = (float*)d_out;

    char* ws = (char*)d_ws;
    const size_t szA = (size_t)B_ * C_ * HW_ * sizeof(bf16);  // 18,022,400 B
    float* th   = (float*)ws;
    bf16* slotA = (bf16*)(ws + 4096);
    bf16* slotB = (bf16*)(ws + 4096 + szA);
    float* a0map = (float*)slotB;  // reused AFTER feat_agg is consumed

    theta_kernel<<<1, 32, 0, stream>>>(pt, th);

    dim3 gw((HW_ + 255) / 256, C_, B_);  // 138 x 64 x 4
    // feat_agg -> slotB, vox_agg -> slotA
    warp_max_kernel<<<gw, 256, 0, stream>>>(x, vox, th, slotB, slotA);

    dim3 gc((HW_ + 255) / 256, C_ / 4, B_);  // 138 x 16 x 4
    // ve = conv(vox_agg) -> d_out (fp32)
    conv3x3_kernel<float><<<gc, 256, 0, stream>>>(slotA, vw, vb, vg, vbt, out);
    // fe = conv(feat_agg) -> slotA bf16 (vox_agg dead now)
    conv3x3_kernel<bf16><<<gc, 256, 0, stream>>>(slotB, fw, fb, fg, fbt, slotA);

    // a0map -> slotB front (feat_agg dead now)
    attn_kernel<<<(B_ * HW_) / 8, 256, 0, stream>>>(out, slotA, aw1, ab1, aw2, ab2, a0map);

    // out = ego + a0*out(ve) + (1-a0)*slotA(fe), in-place on d_out
    fuse_kernel<<<gw, 256, 0, stream>>>(x, slotA, a0map, out);
}